// Round 7
// baseline (201.104 us; speedup 1.0000x reference)
//
#include <hip/hip_runtime.h>
#include <hip/hip_bf16.h>
#include <math.h>

typedef __attribute__((ext_vector_type(8))) short short8;
typedef __attribute__((ext_vector_type(4))) short short4v;
typedef __attribute__((ext_vector_type(4))) float float4v;
typedef unsigned short ushort_t;

constexpr int NPTS = 32768;  // B*N
constexpr int NN   = 16384;  // points per batch
constexpr int KK   = 32;     // neighbors
constexpr int CC   = 128;    // channels
constexpr int GRP  = 16;     // points per block -> grid 2048
constexpr int SR   = 136;    // res LDS row stride (shorts): 272 B -> 2-way banks (free)
#define LN_EPS 1e-5f

// d_ws layout (bytes)
constexpr size_t WS_WP   = 0;        // W' swizzled: 20*128*8 bf16 = 40960 B
constexpr size_t WS_WO   = 40960;    // w_out swizzled: 128*128 bf16 = 32768 B
constexpr size_t WS_BE   = 73728;    // beff: 128 f32 = 512 B
constexpr size_t WS_FB   = 74240;    // features bf16: 32768*128*2 = 8388608 B
constexpr size_t WS_NEED = WS_FB + (size_t)NPTS * CC * 2;

__device__ __forceinline__ short f2bs(float x) {
    return (short)__builtin_bit_cast(unsigned short, __float2bfloat16(x));
}
__device__ __forceinline__ float bs2f(ushort_t u) {
    return __uint_as_float(((unsigned)u) << 16);
}

// ---------------- unified prep: blk0 = W' fold, blk1 = w_out swizzle, blk>=2 = f32->bf16 convert ----
__global__ __launch_bounds__(256) void prep_all(
    const float* __restrict__ features,
    const float* __restrict__ w_pos, const float* __restrict__ b_pos,
    const float* __restrict__ w_gcm, const float* __restrict__ b_gcm,
    const float* __restrict__ w_out,
    short* __restrict__ wsWp, short* __restrict__ wsWo, float* __restrict__ wsBeff,
    ushort_t* __restrict__ featbf)
{
    __shared__ float sW[128 * 128];
    __shared__ float sPG[10 * 128];
    __shared__ float sWP[10 * 128];
    __shared__ float sBP[128];
    const int t = threadIdx.x, blk = blockIdx.x;

    if (blk >= 2) {            // ---- feature convert: 2048 float4 per block, fully coalesced ----
        const int base = (blk - 2) * 2048 + t;
        #pragma unroll
        for (int i = 0; i < 8; ++i) {
            const int f4 = base + i * 256;
            const float4 a = ((const float4*)features)[f4];
            short4v v; v[0]=f2bs(a.x); v[1]=f2bs(a.y); v[2]=f2bs(a.z); v[3]=f2bs(a.w);
            ((short4v*)featbf)[f4] = v;
        }
        return;
    }
    if (blk == 1) {            // ---- w_out: coalesced stage -> swizzle [(k/8)(n)(k%8)] ----
        for (int e = t; e < 4096; e += 256) ((float4*)sW)[e] = ((const float4*)w_out)[e];
        __syncthreads();
        for (int e = t; e < 128 * 128; e += 256) {
            int j = e & 7, n = (e >> 3) & 127, g = e >> 10;
            wsWo[e] = f2bs(sW[(g * 8 + j) * 128 + n]);
        }
        return;
    }
    // ---- blk 0: stage EVERYTHING to LDS first (kills the serial global-load chain) ----
    for (int e = t; e < 1280; e += 256) sWP[e] = w_pos[e];
    if (t < 128) sBP[t] = b_pos[t];
    for (int e = t; e < 4096; e += 256) ((float4*)sW)[e] = ((const float4*)w_gcm)[e];
    __syncthreads();
    {
        const int c = t & 127, gb = t >> 7;
        for (int gi = 0; gi < 5; ++gi) {
            const int g = gi * 2 + gb;
            float s = 0.f;
            for (int r = 0; r < 128; ++r) s += sWP[g * 128 + r] * sW[r * 128 + c];
            sPG[g * 128 + c] = s;
        }
        if (t < 128) {
            float wb = b_gcm[t];
            for (int r = 0; r < 128; ++r) wb += sBP[r] * sW[r * 128 + t];
            wsBeff[t] = wb;
        }
    }
    __syncthreads();
    for (int e = t; e < 20 * 128 * 8; e += 256) {
        const int j = e & 7, n = (e >> 3) & 127, g = e >> 10;
        const int k = g * 8 + j;
        const float v = (k < 128) ? sW[k * 128 + n] : (k < 138 ? sPG[(k - 128) * 128 + n] : 0.f);
        wsWp[e] = f2bs(v);
    }
}

// ---------------- main: direct global->VGPR A-fragments, zero barriers in the K loop ----------------
// wave = (ph = point-in-pair, ch = column half). Per wave per pair: 8 16B gather loads
// + in-register geo fragments -> 40 MFMA. No sA/sG LDS, no __syncthreads until epilogue.
template<int DMA>
__global__ __launch_bounds__(256, 2) void bridge_main(
    const float* __restrict__ points, const float* __restrict__ features,
    const int*   __restrict__ gidx,
    const short* __restrict__ wsWp, const short* __restrict__ wsWo,
    const float* __restrict__ wsBeff, const ushort_t* __restrict__ featbf,
    const float* __restrict__ b_out, const float* __restrict__ ln_g,
    const float* __restrict__ ln_b,
    float* __restrict__ out)
{
    __shared__ short sRes[GRP * SR];
    __shared__ int   sIdx[GRP * KK];
    __shared__ float sPS[4][GRP], sPQ[4][GRP];

    const int t = threadIdx.x, wv = t >> 6;
    const int quad = (t >> 4) & 3, m = t & 15;
    const int ph = wv >> 1;               // point-in-pair this wave owns
    const int ch = wv & 1;                // column half (0: 0-63, 1: 64-127)
    const int g0 = blockIdx.x * GRP;
    const int nbase = (g0 >= NN) ? NN : 0;

    sIdx[t]       = gidx[(size_t)g0 * KK + t];
    sIdx[t + 256] = gidx[(size_t)g0 * KK + t + 256];

    // ---- B fragments (4 n-tiles x 5 k-steps, register-resident) ----
    short8 bWp[5][4];
    #pragma unroll
    for (int ks = 0; ks < 5; ++ks)
        #pragma unroll
        for (int n = 0; n < 4; ++n)
            bWp[ks][n] = ((const short8*)wsWp)[(ks * 4 + quad) * 128 + ch * 64 + n * 16 + m];
    float beffv[4];
    #pragma unroll
    for (int n = 0; n < 4; ++n) beffv[n] = wsBeff[ch * 64 + n * 16 + m];

    __syncthreads();   // sIdx ready (only barrier before epilogue)

    // ---- double-buffered per-wave pipeline state (registers) ----
    short8 A[2][2][4];                  // [buf][mtile][kstep] feature frags
    short8 G[2][2];                     // [buf][mtile] geo frags (quad-selected)
    float  rs[2][4];                    // residual features (own point)
    float  npx[2][2], npy[2][2], npz[2][2], cpx[2], cpy[2], cpz[2];

    auto load_pair = [&](int P, int b) {
        const int prow = P * 2 + ph;
        const int pt = g0 + prow;
        #pragma unroll
        for (int mt = 0; mt < 2; ++mt) {
            const int kn = nbase + sIdx[prow * KK + mt * 16 + m];
            if constexpr (DMA) {
                const ushort_t* rp = featbf + (size_t)kn * CC + quad * 8;
                #pragma unroll
                for (int ks = 0; ks < 4; ++ks)
                    A[b][mt][ks] = *(const short8*)(rp + ks * 32);
            } else {
                const float* rp = features + (size_t)kn * CC + quad * 8;
                #pragma unroll
                for (int ks = 0; ks < 4; ++ks) {
                    const float4 x = ((const float4*)rp)[ks * 8];
                    const float4 y = ((const float4*)rp)[ks * 8 + 1];
                    short8 v;
                    v[0]=f2bs(x.x); v[1]=f2bs(x.y); v[2]=f2bs(x.z); v[3]=f2bs(x.w);
                    v[4]=f2bs(y.x); v[5]=f2bs(y.y); v[6]=f2bs(y.z); v[7]=f2bs(y.w);
                    A[b][mt][ks] = v;
                }
            }
            npx[b][mt] = points[(size_t)kn * 3 + 0];
            npy[b][mt] = points[(size_t)kn * 3 + 1];
            npz[b][mt] = points[(size_t)kn * 3 + 2];
        }
        cpx[b] = points[(size_t)pt * 3 + 0];
        cpy[b] = points[(size_t)pt * 3 + 1];
        cpz[b] = points[(size_t)pt * 3 + 2];
        #pragma unroll
        for (int n = 0; n < 4; ++n) {
            if constexpr (DMA) rs[b][n] = bs2f(featbf[(size_t)pt * CC + ch * 64 + n * 16 + m]);
            else               rs[b][n] = features[(size_t)pt * CC + ch * 64 + n * 16 + m];
        }
    };
    auto make_geo = [&](int b) {
        #pragma unroll
        for (int mt = 0; mt < 2; ++mt) {
            const float dx = npx[b][mt] - cpx[b];
            const float dy = npy[b][mt] - cpy[b];
            const float dz = npz[b][mt] - cpz[b];
            const float dist = sqrtf(dx * dx + dy * dy + dz * dz);
            short8 v0, v1 = (short8)0;
            const short8 z8 = (short8)0;
            v0[0]=f2bs(cpx[b]); v0[1]=f2bs(cpy[b]); v0[2]=f2bs(cpz[b]);
            v0[3]=f2bs(npx[b][mt]); v0[4]=f2bs(npy[b][mt]); v0[5]=f2bs(npz[b][mt]);
            v0[6]=f2bs(dx); v0[7]=f2bs(dy);
            v1[0]=f2bs(dz); v1[1]=f2bs(dist);
            G[b][mt] = (quad == 0) ? v0 : ((quad == 1) ? v1 : z8);
        }
    };

    load_pair(0, 0);
    make_geo(0);

    #pragma unroll
    for (int pair = 0; pair < GRP / 2; ++pair) {
        const int cb = pair & 1, nb = cb ^ 1;
        if (pair < GRP / 2 - 1) load_pair(pair + 1, nb);   // prefetch in flight over MFMA

        float4v acc[2][4] = {};    // [mtile][ntile]
        #pragma unroll
        for (int ks = 0; ks < 4; ++ks)
            #pragma unroll
            for (int mt = 0; mt < 2; ++mt)
                #pragma unroll
                for (int n = 0; n < 4; ++n)
                    acc[mt][n] = __builtin_amdgcn_mfma_f32_16x16x32_bf16(A[cb][mt][ks], bWp[ks][n], acc[mt][n], 0, 0, 0);
        #pragma unroll
        for (int mt = 0; mt < 2; ++mt)
            #pragma unroll
            for (int n = 0; n < 4; ++n)
                acc[mt][n] = __builtin_amdgcn_mfma_f32_16x16x32_bf16(G[cb][mt], bWp[4][n], acc[mt][n], 0, 0, 0);

        if (pair < GRP / 2 - 1) make_geo(nb);

        // ---- relu + max-pool over 32 neighbors, residual, stash res (no barrier) ----
        const int prow = pair * 2 + ph;
        #pragma unroll
        for (int n = 0; n < 4; ++n) {
            float v = acc[0][n][0];
            #pragma unroll
            for (int r = 1; r < 4; ++r) v = fmaxf(v, acc[0][n][r]);
            #pragma unroll
            for (int r = 0; r < 4; ++r) v = fmaxf(v, acc[1][n][r]);
            v = fmaxf(v, __shfl_xor(v, 16));
            v = fmaxf(v, __shfl_xor(v, 32));
            v = fmaxf(v + beffv[n], 0.f);
            const float res = v + rs[cb][n];
            if (quad == 0) sRes[prow * SR + ch * 64 + n * 16 + m] = f2bs(res);
        }
    }
    __syncthreads();   // sRes complete

    // ---- out projection: res(16x128) @ w_out(128x128); wave covers its 64 cols ----
    short8 bWo[4][4];
    #pragma unroll
    for (int ks = 0; ks < 4; ++ks)
        #pragma unroll
        for (int n = 0; n < 4; ++n)
            bWo[ks][n] = ((const short8*)wsWo)[(ks * 4 + quad) * 128 + ch * 64 + n * 16 + m];

    const short* rm = sRes + m * SR;
    float4v acc2[4] = {};
    #pragma unroll
    for (int ks = 0; ks < 4; ++ks) {
        const short8 a = *(const short8*)(rm + (ks * 4 + quad) * 8);
        #pragma unroll
        for (int n = 0; n < 4; ++n)
            acc2[n] = __builtin_amdgcn_mfma_f32_16x16x32_bf16(a, bWo[ks][n], acc2[n], 0, 0, 0);
    }

    float boutv[4], lngv[4], lnbv[4];
    #pragma unroll
    for (int n = 0; n < 4; ++n) {
        const int c = ch * 64 + n * 16 + m;
        boutv[n] = b_out[c]; lngv[n] = ln_g[c]; lnbv[n] = ln_b[c];
    }

    #pragma unroll
    for (int r = 0; r < 4; ++r) {
        float ss = 0.f, qq = 0.f;
        #pragma unroll
        for (int n = 0; n < 4; ++n) {
            const float o = acc2[n][r] + boutv[n];
            ss += o; qq += o * o;
        }
        #pragma unroll
        for (int d = 1; d < 16; d <<= 1) { ss += __shfl_xor(ss, d); qq += __shfl_xor(qq, d); }
        if (m == 0) { sPS[wv][quad * 4 + r] = ss; sPQ[wv][quad * 4 + r] = qq; }
    }
    __syncthreads();

    if (wv < 2) {   // waves 0/1 cover all 128 cols; ph-duplicated partials summed and halved
        #pragma unroll
        for (int r = 0; r < 4; ++r) {
            const int R = quad * 4 + r;
            const float S = (sPS[0][R] + sPS[1][R] + sPS[2][R] + sPS[3][R]) * 0.5f;
            const float Q = (sPQ[0][R] + sPQ[1][R] + sPQ[2][R] + sPQ[3][R]) * 0.5f;
            const float mu  = S * (1.f / 128.f);
            const float var = fmaxf(Q * (1.f / 128.f) - mu * mu, 0.f);
            const float rstd = rsqrtf(var + LN_EPS);
            const size_t base = (size_t)(g0 + R) * CC;
            #pragma unroll
            for (int n = 0; n < 4; ++n) {
                const float o = acc2[n][r] + boutv[n];
                out[base + ch * 64 + n * 16 + m] = fmaxf((o - mu) * rstd * lngv[n] + lnbv[n], 0.f);
            }
        }
    }
}

extern "C" void kernel_launch(void* const* d_in, const int* in_sizes, int n_in,
                              void* d_out, int out_size, void* d_ws, size_t ws_size,
                              hipStream_t stream) {
    const float* points   = (const float*)d_in[0];
    const float* features = (const float*)d_in[1];
    const int*   gidx     = (const int*)  d_in[2];
    const float* w_pos    = (const float*)d_in[3];
    const float* b_pos    = (const float*)d_in[4];
    const float* w_gcm    = (const float*)d_in[5];
    const float* b_gcm    = (const float*)d_in[6];
    const float* w_out    = (const float*)d_in[7];
    const float* b_out    = (const float*)d_in[8];
    const float* ln_g     = (const float*)d_in[9];
    const float* ln_b     = (const float*)d_in[10];
    float* out = (float*)d_out;

    char* ws = (char*)d_ws;
    short*    wsWp   = (short*)(ws + WS_WP);
    short*    wsWo   = (short*)(ws + WS_WO);
    float*    wsBeff = (float*)(ws + WS_BE);
    ushort_t* featbf = (ushort_t*)(ws + WS_FB);

    const bool use_dma = (ws_size >= WS_NEED);
    const int prep_blocks = use_dma ? (2 + (NPTS * CC / 4) / 2048) : 2;   // 2 + 512

    hipLaunchKernelGGL(prep_all, dim3(prep_blocks), dim3(256), 0, stream,
                       features, w_pos, b_pos, w_gcm, b_gcm, w_out,
                       wsWp, wsWo, wsBeff, featbf);
    if (use_dma) {
        hipLaunchKernelGGL((bridge_main<1>), dim3(NPTS / GRP), dim3(256), 0, stream,
                           points, features, gidx, wsWp, wsWo, wsBeff, featbf,
                           b_out, ln_g, ln_b, out);
    } else {
        hipLaunchKernelGGL((bridge_main<0>), dim3(NPTS / GRP), dim3(256), 0, stream,
                           points, features, gidx, wsWp, wsWo, wsBeff, featbf,
                           b_out, ln_g, ln_b, out);
    }
}

// Round 8
// 162.743 us; speedup vs baseline: 1.2357x; 1.2357x over previous
//
#include <hip/hip_runtime.h>
#include <hip/hip_bf16.h>
#include <math.h>

typedef __attribute__((ext_vector_type(8))) short short8;
typedef __attribute__((ext_vector_type(4))) short short4v;
typedef __attribute__((ext_vector_type(4))) float float4v;
typedef unsigned short ushort_t;

constexpr int NPTS = 32768;  // B*N
constexpr int NN   = 16384;  // points per batch
constexpr int KK   = 32;     // neighbors
constexpr int CC   = 128;    // channels
constexpr int GRP  = 16;     // points per block -> grid 2048
constexpr int SG   = 40;     // geo LDS row stride (shorts): 80 B -> 2-way banks (free)
constexpr int SR   = 136;    // res LDS row stride (shorts): 272 B -> 2-way banks (free)
#define LN_EPS 1e-5f

// d_ws layout (bytes)
constexpr size_t WS_WP   = 0;        // W' swizzled: 20*128*8 bf16 = 40960 B
constexpr size_t WS_WO   = 40960;    // w_out swizzled: 128*128 bf16 = 32768 B
constexpr size_t WS_BE   = 73728;    // beff: 128 f32 = 512 B
constexpr size_t WS_PG   = 74240;    // PG = w_pos@w_gcm: 10*128 f32 = 5120 B
constexpr size_t WS_FB   = 79360;    // features bf16: 32768*128*2 = 8388608 B
constexpr size_t WS_NEED = WS_FB + (size_t)NPTS * CC * 2;

__device__ __forceinline__ short f2bs(float x) {
    return (short)__builtin_bit_cast(unsigned short, __float2bfloat16(x));
}
__device__ __forceinline__ float bs2f(ushort_t u) {
    return __uint_as_float(((unsigned)u) << 16);
}

// ---------------- prep stage 1: fold (one 128-dot per thread, fully parallel) ----------------
// blocks 0..9: PG[g][c] = sum_r w_pos[g][r] * w_gcm[r][c]   (block g, thread c)
// block 10   : beff[c]  = b_gcm[c] + sum_r b_pos[r] * w_gcm[r][c]
__global__ __launch_bounds__(128) void prep_fold(
    const float* __restrict__ w_pos, const float* __restrict__ b_pos,
    const float* __restrict__ w_gcm, const float* __restrict__ b_gcm,
    float* __restrict__ wsPG, float* __restrict__ wsBeff)
{
    const int c = threadIdx.x, g = blockIdx.x;
    if (g < 10) {
        float s = 0.f;
        #pragma unroll
        for (int r = 0; r < 128; ++r) s += w_pos[g * 128 + r] * w_gcm[r * 128 + c];
        wsPG[g * 128 + c] = s;
    } else {
        float s = b_gcm[c];
        #pragma unroll
        for (int r = 0; r < 128; ++r) s += b_pos[r] * w_gcm[r * 128 + c];
        wsBeff[c] = s;
    }
}

// ---------------- prep stage 2: swizzles + feature f32->bf16 convert (all parallel) ----------------
// blocks 0..511: feature convert. 512: wsWp k<128. 513: wsWp k>=128 (reads PG). 514: wsWo.
__global__ __launch_bounds__(256) void prep_pack(
    const float* __restrict__ features, const float* __restrict__ w_gcm,
    const float* __restrict__ w_out, const float* __restrict__ wsPG,
    short* __restrict__ wsWp, short* __restrict__ wsWo, ushort_t* __restrict__ featbf,
    int do_convert)
{
    const int t = threadIdx.x, blk = blockIdx.x;
    if (blk < 512) {
        if (!do_convert) return;
        const int base = blk * 2048 + t;
        #pragma unroll
        for (int i = 0; i < 8; ++i) {
            const int f4 = base + i * 256;
            const float4 a = ((const float4*)features)[f4];
            short4v v; v[0]=f2bs(a.x); v[1]=f2bs(a.y); v[2]=f2bs(a.z); v[3]=f2bs(a.w);
            ((short4v*)featbf)[f4] = v;
        }
        return;
    }
    if (blk == 512) {          // W' region k<128: packed (g,n,j), k=8g+j
        #pragma unroll 4
        for (int e = t; e < 16 * 128 * 8; e += 256) {
            const int j = e & 7, n = (e >> 3) & 127, g = e >> 10;
            wsWp[e] = f2bs(w_gcm[(g * 8 + j) * 128 + n]);
        }
        return;
    }
    if (blk == 513) {          // W' region k in [128,160): PG rows then zeros
        #pragma unroll 4
        for (int e2 = t; e2 < 4 * 128 * 8; e2 += 256) {
            const int e = 16 * 128 * 8 + e2;
            const int j = e & 7, n = (e >> 3) & 127, g = e >> 10;
            const int k = g * 8 + j;
            wsWp[e] = (k < 138) ? f2bs(wsPG[(k - 128) * 128 + n]) : (short)0;
        }
        return;
    }
    // blk == 514: w_out swizzle
    #pragma unroll 4
    for (int e = t; e < 128 * 128; e += 256) {
        const int j = e & 7, n = (e >> 3) & 127, g = e >> 10;
        wsWo[e] = f2bs(w_out[(g * 8 + j) * 128 + n]);
    }
}

// ---------------- main kernel (R5 champion, verbatim): DMA gather to LDS, per-point loop ----------------
template<int DMA>
__global__ __launch_bounds__(256) void bridge_main(
    const float* __restrict__ points, const float* __restrict__ features,
    const int*   __restrict__ gidx,
    const short* __restrict__ wsWp, const short* __restrict__ wsWo,
    const float* __restrict__ wsBeff, const ushort_t* __restrict__ featbf,
    const float* __restrict__ b_out, const float* __restrict__ ln_g,
    const float* __restrict__ ln_b,
    float* __restrict__ out)
{
    __shared__ short sA[2][KK * CC];    // gathered features, 256B rows, XOR-chunk-swizzled
    __shared__ short sG[2][KK * SG];    // geo cols 128..159 (10 real + zeros), padded stride
    __shared__ short sRes[GRP * SR];
    __shared__ int   sIdx[GRP * KK];    // 512 neighbor indices
    __shared__ float sPS[4][GRP], sPQ[4][GRP];

    const int t = threadIdx.x, wv = t >> 6, lane = t & 63;
    const int quad = (t >> 4) & 3, m = t & 15;
    const int g0 = blockIdx.x * GRP;
    const int nbase = (g0 >= NN) ? NN : 0;    // batch base (GRP divides NN)
    const int col0 = wv * 32 + m;

    // ---- stage idx, zero geo pad columns ----
    sIdx[t]       = gidx[(size_t)g0 * KK + t];
    sIdx[t + 256] = gidx[(size_t)g0 * KK + t + 256];
    if (t < 128) {
        const int b = t >> 6, r = (t >> 1) & 31, h = t & 1;
        *(short8*)&sG[b][r * SG + 16 + h * 8] = (short8)0;
    }

    // ---- B fragments + per-column constants ----
    short8 bWp[5][2];
    #pragma unroll
    for (int ks = 0; ks < 5; ++ks)
        #pragma unroll
        for (int ntl = 0; ntl < 2; ++ntl)
            bWp[ks][ntl] = *((const short8*)wsWp + ((ks * 4 + quad) * 128 + col0 + ntl * 16));
    float beffv[2] = { wsBeff[col0], wsBeff[col0 + 16] };

    __syncthreads();

    // ---- gather lane mapping: 16 lanes per row, XOR chunk swizzle ----
    const int r0 = wv * 4 + (lane >> 4);  // 0..15 (row r0 and r0+16)
    const int pc = lane & 15;             // physical 16B chunk
    const int gc = pc ^ r0;               // logical chunk; (r0+16)&15 == r0

    float4 ff0a, ff0b, ff1a, ff1b;                    // fallback regs
    float gcx, gcy, gcz, ggx, ggy, ggz;               // geo regs (lane<8)

    auto issue_dma = [&](int p, int buf) {
        const int kn0 = nbase + sIdx[p * KK + r0];
        const int kn1 = nbase + sIdx[p * KK + r0 + 16];
        const ushort_t* gp0 = featbf + (size_t)kn0 * CC + gc * 8;
        const ushort_t* gp1 = featbf + (size_t)kn1 * CC + gc * 8;
        short* l0 = &sA[buf][(wv * 4) * CC];          // wave-uniform; lane i -> +i*16B
        short* l1 = &sA[buf][(wv * 4 + 16) * CC];
        __builtin_amdgcn_global_load_lds((const __attribute__((address_space(1))) void*)gp0,
                                         (__attribute__((address_space(3))) void*)l0, 16, 0, 0);
        __builtin_amdgcn_global_load_lds((const __attribute__((address_space(1))) void*)gp1,
                                         (__attribute__((address_space(3))) void*)l1, 16, 0, 0);
    };
    auto fb_load = [&](int p) {
        const int kn0 = nbase + sIdx[p * KK + r0];
        const int kn1 = nbase + sIdx[p * KK + r0 + 16];
        const float4* f0 = (const float4*)(features + (size_t)kn0 * CC + gc * 8);
        const float4* f1 = (const float4*)(features + (size_t)kn1 * CC + gc * 8);
        ff0a = f0[0]; ff0b = f0[1]; ff1a = f1[0]; ff1b = f1[1];
    };
    auto fb_store = [&](int buf) {
        short8 v;
        v[0]=f2bs(ff0a.x); v[1]=f2bs(ff0a.y); v[2]=f2bs(ff0a.z); v[3]=f2bs(ff0a.w);
        v[4]=f2bs(ff0b.x); v[5]=f2bs(ff0b.y); v[6]=f2bs(ff0b.z); v[7]=f2bs(ff0b.w);
        *(short8*)&sA[buf][r0 * CC + pc * 8] = v;
        v[0]=f2bs(ff1a.x); v[1]=f2bs(ff1a.y); v[2]=f2bs(ff1a.z); v[3]=f2bs(ff1a.w);
        v[4]=f2bs(ff1b.x); v[5]=f2bs(ff1b.y); v[6]=f2bs(ff1b.z); v[7]=f2bs(ff1b.w);
        *(short8*)&sA[buf][(r0 + 16) * CC + pc * 8] = v;
    };
    auto geo_load = [&](int p) {
        if (lane < 8) {
            const int j  = wv * 8 + lane;
            const int pt = g0 + p;
            const int kn = nbase + sIdx[p * KK + j];
            gcx = points[(size_t)pt * 3 + 0]; gcy = points[(size_t)pt * 3 + 1]; gcz = points[(size_t)pt * 3 + 2];
            ggx = points[(size_t)kn * 3 + 0]; ggy = points[(size_t)kn * 3 + 1]; ggz = points[(size_t)kn * 3 + 2];
        }
    };
    auto geo_store = [&](int buf) {
        if (lane < 8) {
            const int j = wv * 8 + lane;
            const float dx = ggx - gcx, dy = ggy - gcy, dz = ggz - gcz;
            const float dist = sqrtf(dx * dx + dy * dy + dz * dz);
            short8 v0, v1 = (short8)0;
            v0[0]=f2bs(gcx); v0[1]=f2bs(gcy); v0[2]=f2bs(gcz);
            v0[3]=f2bs(ggx); v0[4]=f2bs(ggy); v0[5]=f2bs(ggz);
            v0[6]=f2bs(dx);  v0[7]=f2bs(dy);
            v1[0]=f2bs(dz);  v1[1]=f2bs(dist);
            *(short8*)&sG[buf][j * SG + 0] = v0;
            *(short8*)&sG[buf][j * SG + 8] = v1;
        }
    };

    // ---- preload point 0 ----
    if constexpr (DMA) issue_dma(0, 0); else fb_load(0);
    geo_load(0);
    if constexpr (!DMA) fb_store(0);
    geo_store(0);
    __syncthreads();

    // loop-invariant A-fragment offsets (shorts)
    int offA[4];
    #pragma unroll
    for (int ks = 0; ks < 4; ++ks) offA[ks] = m * CC + (((ks * 4 + quad) ^ m) * 8);
    const int offG = m * SG + quad * 8;

    for (int p = 0; p < GRP; ++p) {
        const int buf = p & 1, nbuf = buf ^ 1;
        if (p + 1 < GRP) {
            if constexpr (DMA) issue_dma(p + 1, nbuf); else fb_load(p + 1);
            geo_load(p + 1);
        }

        const short* ab = sA[buf];
        const short* ag = sG[buf];
        float4v acc[2][2] = {};
        #pragma unroll
        for (int ks = 0; ks < 4; ++ks) {
            const short8 a0 = *(const short8*)(ab + offA[ks]);
            const short8 a1 = *(const short8*)(ab + offA[ks] + 16 * CC);
            acc[0][0] = __builtin_amdgcn_mfma_f32_16x16x32_bf16(a0, bWp[ks][0], acc[0][0], 0, 0, 0);
            acc[0][1] = __builtin_amdgcn_mfma_f32_16x16x32_bf16(a0, bWp[ks][1], acc[0][1], 0, 0, 0);
            acc[1][0] = __builtin_amdgcn_mfma_f32_16x16x32_bf16(a1, bWp[ks][0], acc[1][0], 0, 0, 0);
            acc[1][1] = __builtin_amdgcn_mfma_f32_16x16x32_bf16(a1, bWp[ks][1], acc[1][1], 0, 0, 0);
        }
        {
            const short8 a0 = *(const short8*)(ag + offG);
            const short8 a1 = *(const short8*)(ag + offG + 16 * SG);
            acc[0][0] = __builtin_amdgcn_mfma_f32_16x16x32_bf16(a0, bWp[4][0], acc[0][0], 0, 0, 0);
            acc[0][1] = __builtin_amdgcn_mfma_f32_16x16x32_bf16(a0, bWp[4][1], acc[0][1], 0, 0, 0);
            acc[1][0] = __builtin_amdgcn_mfma_f32_16x16x32_bf16(a1, bWp[4][0], acc[1][0], 0, 0, 0);
            acc[1][1] = __builtin_amdgcn_mfma_f32_16x16x32_bf16(a1, bWp[4][1], acc[1][1], 0, 0, 0);
        }

        if (p + 1 < GRP) {
            if constexpr (!DMA) fb_store(nbuf);
            geo_store(nbuf);
        }

        // ---- relu+max-pool over 32 neighbors, residual, stash res ----
        const int pt = g0 + p;
        #pragma unroll
        for (int ntl = 0; ntl < 2; ++ntl) {
            float v = acc[0][ntl][0];
            #pragma unroll
            for (int r = 1; r < 4; ++r) v = fmaxf(v, acc[0][ntl][r]);
            #pragma unroll
            for (int r = 0; r < 4; ++r) v = fmaxf(v, acc[1][ntl][r]);
            v = fmaxf(v, __shfl_xor(v, 16));
            v = fmaxf(v, __shfl_xor(v, 32));
            v = fmaxf(v + beffv[ntl], 0.f);
            float fc;
            if constexpr (DMA) fc = bs2f(featbf[(size_t)pt * CC + col0 + ntl * 16]);
            else               fc = features[(size_t)pt * CC + col0 + ntl * 16];
            const float res = v + fc;
            if (quad == 0) sRes[p * SR + col0 + ntl * 16] = f2bs(res);
        }
        __syncthreads();
    }

    // ---- out projection: res(16x128) @ w_out(128x128) ----
    short8 bWo[4][2];
    #pragma unroll
    for (int ks = 0; ks < 4; ++ks)
        #pragma unroll
        for (int ntl = 0; ntl < 2; ++ntl)
            bWo[ks][ntl] = *((const short8*)wsWo + ((ks * 4 + quad) * 128 + col0 + ntl * 16));

    const short* rm = sRes + m * SR;
    float4v acc2[2] = {};
    #pragma unroll
    for (int ks = 0; ks < 4; ++ks) {
        const short8 a = *(const short8*)(rm + ks * 32 + quad * 8);
        acc2[0] = __builtin_amdgcn_mfma_f32_16x16x32_bf16(a, bWo[ks][0], acc2[0], 0, 0, 0);
        acc2[1] = __builtin_amdgcn_mfma_f32_16x16x32_bf16(a, bWo[ks][1], acc2[1], 0, 0, 0);
    }

    const float boutv[2] = { b_out[col0], b_out[col0 + 16] };
    const float lngv[2]  = { ln_g[col0], ln_g[col0 + 16] };
    const float lnbv[2]  = { ln_b[col0], ln_b[col0 + 16] };

    #pragma unroll
    for (int r = 0; r < 4; ++r) {
        const float o0 = acc2[0][r] + boutv[0];
        const float o1 = acc2[1][r] + boutv[1];
        float ss = o0 + o1, qq = o0 * o0 + o1 * o1;
        #pragma unroll
        for (int d = 1; d < 16; d <<= 1) { ss += __shfl_xor(ss, d); qq += __shfl_xor(qq, d); }
        if (m == 0) { sPS[wv][quad * 4 + r] = ss; sPQ[wv][quad * 4 + r] = qq; }
    }
    __syncthreads();

    #pragma unroll
    for (int r = 0; r < 4; ++r) {
        const int R = quad * 4 + r;
        const float S = sPS[0][R] + sPS[1][R] + sPS[2][R] + sPS[3][R];
        const float Q = sPQ[0][R] + sPQ[1][R] + sPQ[2][R] + sPQ[3][R];
        const float mu  = S * (1.f / 128.f);
        const float var = fmaxf(Q * (1.f / 128.f) - mu * mu, 0.f);
        const float rstd = rsqrtf(var + LN_EPS);
        const float o0 = acc2[0][r] + boutv[0];
        const float o1 = acc2[1][r] + boutv[1];
        const size_t base = (size_t)(g0 + R) * CC;
        out[base + col0]      = fmaxf((o0 - mu) * rstd * lngv[0] + lnbv[0], 0.f);
        out[base + col0 + 16] = fmaxf((o1 - mu) * rstd * lngv[1] + lnbv[1], 0.f);
    }
}

extern "C" void kernel_launch(void* const* d_in, const int* in_sizes, int n_in,
                              void* d_out, int out_size, void* d_ws, size_t ws_size,
                              hipStream_t stream) {
    const float* points   = (const float*)d_in[0];
    const float* features = (const float*)d_in[1];
    const int*   gidx     = (const int*)  d_in[2];
    const float* w_pos    = (const float*)d_in[3];
    const float* b_pos    = (const float*)d_in[4];
    const float* w_gcm    = (const float*)d_in[5];
    const float* b_gcm    = (const float*)d_in[6];
    const float* w_out    = (const float*)d_in[7];
    const float* b_out    = (const float*)d_in[8];
    const float* ln_g     = (const float*)d_in[9];
    const float* ln_b     = (const float*)d_in[10];
    float* out = (float*)d_out;

    char* ws = (char*)d_ws;
    short*    wsWp   = (short*)(ws + WS_WP);
    short*    wsWo   = (short*)(ws + WS_WO);
    float*    wsBeff = (float*)(ws + WS_BE);
    float*    wsPG   = (float*)(ws + WS_PG);
    ushort_t* featbf = (ushort_t*)(ws + WS_FB);

    const bool use_dma = (ws_size >= WS_NEED);

    hipLaunchKernelGGL(prep_fold, dim3(11), dim3(128), 0, stream,
                       w_pos, b_pos, w_gcm, b_gcm, wsPG, wsBeff);
    hipLaunchKernelGGL(prep_pack, dim3(515), dim3(256), 0, stream,
                       features, w_gcm, w_out, wsPG, wsWp, wsWo, featbf,
                       use_dma ? 1 : 0);
    if (use_dma) {
        hipLaunchKernelGGL((bridge_main<1>), dim3(NPTS / GRP), dim3(256), 0, stream,
                           points, features, gidx, wsWp, wsWo, wsBeff, featbf,
                           b_out, ln_g, ln_b, out);
    } else {
        hipLaunchKernelGGL((bridge_main<0>), dim3(NPTS / GRP), dim3(256), 0, stream,
                           points, features, gidx, wsWp, wsWo, wsBeff, featbf,
                           b_out, ln_g, ln_b, out);
    }
}